// Round 9
// baseline (239.732 us; speedup 1.0000x reference)
//
#include <hip/hip_runtime.h>
#include <hip/hip_bf16.h>

// Problem constants
#define SEQ   2048
#define BATCH 4
#define DM    768
#define NH    12
#define HD    64
#define MTOT  (BATCH*SEQ)   // 8192

typedef short bf16x8 __attribute__((ext_vector_type(8)));   // 8 bf16 = 4 VGPRs
typedef float f32x4  __attribute__((ext_vector_type(4)));

static __device__ __forceinline__ short f2bf(float f) {
  union { __hip_bfloat16 h; short s; } u;
  u.h = __float2bfloat16(f);
  return u.s;
}

// async global->LDS, 16 B per lane (global_load_lds_dwordx4)
static __device__ __forceinline__ void async_cp16(const short* g, short* l) {
  __builtin_amdgcn_global_load_lds(
      (const __attribute__((address_space(1))) void*)g,
      (__attribute__((address_space(3))) void*)l, 16, 0, 0);
}

// ------------------------------------------- fused fp32 -> bf16 (x + 4 weights)
__global__ void cvt5_kernel(const float* __restrict__ x, const float* __restrict__ wq,
                            const float* __restrict__ wk, const float* __restrict__ wv,
                            const float* __restrict__ wo, short* __restrict__ dst) {
  const int NX4 = MTOT * DM / 4, NW4 = DM * DM / 4, TOT4 = NX4 + 4 * NW4;
  int i = blockIdx.x * blockDim.x + threadIdx.x;
  if (i >= TOT4) return;
  const float* src; int off;
  if (i < NX4) { src = x; off = i; }
  else {
    int j = i - NX4; int sel = j / NW4; off = j - sel * NW4;
    src = (sel == 0) ? wq : (sel == 1) ? wk : (sel == 2) ? wv : wo;
  }
  float4 v = reinterpret_cast<const float4*>(src)[off];
  short4 o;
  o.x = f2bf(v.x); o.y = f2bf(v.y); o.z = f2bf(v.z); o.w = f2bf(v.w);
  reinterpret_cast<short4*>(dst)[i] = o;
}

// ---------------------------------------------- m97-style 128x128 LDS-staged GEMM core
static __device__ __forceinline__ void gemm_lds_core(
    const short* __restrict__ A, const short* __restrict__ W,
    short* As, short* Bs, int m0, int n0, f32x4 acc[4][4])
{
  const int t = threadIdx.x;
  const int lane = t & 63, w = t >> 6;
  const int quad = lane >> 4, lq = lane & 15;
  const int mw = (w & 1) * 64, nw = (w >> 1) * 64;
  const int r0 = t >> 2, c0 = (t & 3) * 8;
  const short* ga0 = A + (size_t)(m0 + r0) * DM + c0;
  const short* ga1 = A + (size_t)(m0 + 64 + r0) * DM + c0;
  const short* gb0 = W + (size_t)(n0 + r0) * DM + c0;
  const short* gb1 = W + (size_t)(n0 + 64 + r0) * DM + c0;
  short* la0 = As + t * 8;
  short* la1 = As + 2048 + t * 8;
  short* lb0 = Bs + t * 8;
  short* lb1 = Bs + 2048 + t * 8;

  for (int k0 = 0; k0 < DM; k0 += 32) {
    async_cp16(ga0 + k0, la0);
    async_cp16(ga1 + k0, la1);
    async_cp16(gb0 + k0, lb0);
    async_cp16(gb1 + k0, lb1);
    __syncthreads();
    bf16x8 af[4], bf[4];
#pragma unroll
    for (int i = 0; i < 4; ++i) {
      af[i] = *(const bf16x8*)(As + (mw + i * 16 + lq) * 32 + quad * 8);
      bf[i] = *(const bf16x8*)(Bs + (nw + i * 16 + lq) * 32 + quad * 8);
    }
#pragma unroll
    for (int mt = 0; mt < 4; ++mt)
#pragma unroll
      for (int nt = 0; nt < 4; ++nt)
        acc[mt][nt] = __builtin_amdgcn_mfma_f32_16x16x32_bf16(af[mt], bf[nt], acc[mt][nt], 0, 0, 0);
    __syncthreads();
  }
}

// --------------------------------------------------------------- fused QKV projection
__global__ __launch_bounds__(256) void qkv_gemm(
    const short* __restrict__ xb, const short* __restrict__ Wall,
    short* __restrict__ Qb, short* __restrict__ Kb, short* __restrict__ VTb)
{
  __shared__ __align__(16) short As[4096], Bs[4096];
  const int m0 = blockIdx.y * 128, n0 = blockIdx.x * 128;
  f32x4 acc[4][4] = {};
  gemm_lds_core(xb, Wall, As, Bs, m0, n0, acc);

  const int t = threadIdx.x;
  const int lane = t & 63, w = t >> 6;
  const int quad = lane >> 4, lq = lane & 15;
  const int mwb = m0 + (w & 1) * 64, nwb = n0 + (w >> 1) * 64;
#pragma unroll
  for (int mt = 0; mt < 4; ++mt)
#pragma unroll
    for (int nt = 0; nt < 4; ++nt) {
      const int n = nwb + nt * 16 + lq;
      const int z = n / DM, nn = n % DM;
      const int h = nn >> 6, d = nn & 63;
      const int mbase = mwb + mt * 16 + quad * 4;
      const int b = mbase >> 11, s0 = mbase & 2047;
      if (z == 2) {
        short4 v;
        v.x = f2bf(acc[mt][nt][0]); v.y = f2bf(acc[mt][nt][1]);
        v.z = f2bf(acc[mt][nt][2]); v.w = f2bf(acc[mt][nt][3]);
        *(short4*)(VTb + ((size_t)(b * NH + h) * HD + d) * SEQ + s0) = v;
      } else {
        short* dst = (z == 0) ? Qb : Kb;
#pragma unroll
        for (int r = 0; r < 4; ++r)
          dst[((size_t)(b * NH + h) * SEQ + s0 + r) * HD + d] = f2bf(acc[mt][nt][r]);
      }
    }
}

// ------------------------------------------------------------ flash attention
// R7 semantics with three SAFE deltas (mask stays UNCONDITIONAL — every kernel
// that gated the st-mask in control flow miscomputed; see R4/R6/R8 bisect):
//  (1) l row-sum via ones-A MFMA into lacc (C-layout: every reg = l(q));
//      rescale multiplies lacc inside the same __all identity-skip.
//  (2) exp arg as one fma; packed bf16 cvt for P.
//  (3) g-striped block mapping (g = bp&15) to even per-CU staging trip counts.
__global__ __launch_bounds__(256) void attn_kernel(
    const short* __restrict__ Qb, const short* __restrict__ Kb,
    const short* __restrict__ VTb, short* __restrict__ AOb)
{
  __shared__ __align__(16) short Ks[32 * 64];   // [keyoff][hd], chunk-swizzled
  __shared__ __align__(16) short Vs[64 * 32];   // [hd][keyoff]
  const int bp = blockIdx.x;
  const int bh = bp >> 4;              // 0..47  (striped: consecutive bp -> same bh? no: bp>>4)
  const int g  = bp & 15;              // 0..15  cycles fastest -> mixes trip counts per CU
  const int tid = threadIdx.x;
  const int w = tid >> 6, lane = tid & 63;
  const int quad = lane >> 4, lq = lane & 15;
  const int tp = 4 * g + w;            // pair id 0..63
  const int b = bh / NH, h = bh % NH;
  const int q0b = 16 * tp;             // qt0 query base
  const int q1b = 2032 - 16 * tp;      // qt1 query base
  const int E0 = q0b + 16;             // qt0 key range end
  const int E1 = q1b + 16;             // qt1 key range end
  const int Eblk = 2048 - 64 * g;      // block-uniform loop bound (= E1 of w=0)

  const short* Qh = Qb  + (size_t)bh * SEQ * HD;
  const short* Kh = Kb  + (size_t)bh * SEQ * HD;
  const short* Vh = VTb + (size_t)bh * HD * SEQ;

  // Q fragments (B-operand): lane holds Q[qb+lq][hh*32+quad*8+j]
  bf16x8 qf0[2], qf1[2];
#pragma unroll
  for (int hh = 0; hh < 2; ++hh) {
    qf0[hh] = *(const bf16x8*)(Qh + (size_t)(q0b + lq) * HD + hh * 32 + quad * 8);
    qf1[hh] = *(const bf16x8*)(Qh + (size_t)(q1b + lq) * HD + hh * 32 + quad * 8);
  }

  // ones A-fragment for the l row-sum MFMA (bf16 1.0 = 0x3F80)
  bf16x8 onesf;
#pragma unroll
  for (int j = 0; j < 8; ++j) onesf[j] = (short)0x3F80;

  f32x4 o0[4] = {}, o1[4] = {};        // O^T[hd=mt*16+quad*4+r][q=qb+lq]
  f32x4 lacc0 = {}, lacc1 = {};        // l(q) accumulators (all regs equal)
  float m0v = -3e38f, m1v = -3e38f;
  const float Cc = 0.18033688011112042f;  // log2(e)/sqrt(64)

  // ---- K staging, source-swizzled: LDS slot s of row r holds global chunk
  // s^swz(r), swz(r) = (r&3)|(((r>>3)&1)<<2); LDS dest linear (tid*16B).
  const int srow = tid >> 3, sslot = tid & 7;
  const int sswz = (srow & 3) | (((srow >> 3) & 1) << 2);
  const short* gK = Kh + (size_t)srow * HD + (sslot ^ sswz) * 8;
  const short* gV = Vh + (size_t)(tid >> 2) * SEQ + (tid & 3) * 8;
  short* lK = Ks + tid * 8;
  short* lV = Vs + tid * 8;

  // reader-side swizzle: rows 8*(lq>>2)+4*t2+(lq&3) share swz = (lq&3)|(((lq>>2)&1)<<2)
  const int rswz = (lq & 3) | (((lq >> 2) & 1) << 2);

  for (int kb = 0; kb < Eblk; kb += 32) {
    async_cp16(gK + (size_t)kb * HD, lK);
    async_cp16(gV + kb, lV);
    __syncthreads();
    if (kb < E1) {
      const bool act0 = kb < E0;
      // ---- S^T = K.Q^T (K rows permuted so P exits in PV B-operand layout)
      f32x4 st0[2] = {}, st1[2] = {};
#pragma unroll
      for (int t2 = 0; t2 < 2; ++t2) {
        const int row = 8 * (lq >> 2) + 4 * t2 + (lq & 3);
        const int sl0 = quad ^ rswz;
        bf16x8 k0 = *(const bf16x8*)(Ks + row * 64 + sl0 * 8);
        bf16x8 k1 = *(const bf16x8*)(Ks + row * 64 + (sl0 ^ 4) * 8);
        st1[t2] = __builtin_amdgcn_mfma_f32_16x16x32_bf16(k0, qf1[0], st1[t2], 0, 0, 0);
        st1[t2] = __builtin_amdgcn_mfma_f32_16x16x32_bf16(k1, qf1[1], st1[t2], 0, 0, 0);
        if (act0) {
          st0[t2] = __builtin_amdgcn_mfma_f32_16x16x32_bf16(k0, qf0[0], st0[t2], 0, 0, 0);
          st0[t2] = __builtin_amdgcn_mfma_f32_16x16x32_bf16(k1, qf0[1], st0[t2], 0, 0, 0);
        }
      }
      // ---- V fragments (A-operand: rows = hd, k = key offset)
      bf16x8 vf[4];
#pragma unroll
      for (int mt = 0; mt < 4; ++mt)
        vf[mt] = *(const bf16x8*)(Vs + (mt * 16 + lq) * 32 + quad * 8);

      // ================= qt1 softmax (unconditional mask, R7-exact) =========
      bf16x8 pf1;
      {
        const int qv = q1b + lq;
        float mx = -3e38f;
#pragma unroll
        for (int t2 = 0; t2 < 2; ++t2)
#pragma unroll
          for (int r = 0; r < 4; ++r) {
            const int key = kb + 8 * quad + 4 * t2 + r;
            const float v = (key <= qv) ? st1[t2][r] : -3e38f;
            st1[t2][r] = v;
            mx = fmaxf(mx, v);
          }
        mx = fmaxf(mx, __shfl_xor(mx, 16));
        mx = fmaxf(mx, __shfl_xor(mx, 32));
        const float mn = fmaxf(m1v, mx);
        const float al = __builtin_amdgcn_exp2f((m1v - mn) * Cc);
        m1v = mn;
        if (!__all(al == 1.0f)) {       // exact identity skip (mul by 1.0)
#pragma unroll
          for (int r = 0; r < 4; ++r) lacc1[r] *= al;
#pragma unroll
          for (int mt = 0; mt < 4; ++mt)
#pragma unroll
            for (int r = 0; r < 4; ++r)
              o1[mt][r] *= al;
        }
        const float mC = mn * Cc;
        float p[8];
#pragma unroll
        for (int t2 = 0; t2 < 2; ++t2)
#pragma unroll
          for (int r = 0; r < 4; ++r)
            p[t2 * 4 + r] = __builtin_amdgcn_exp2f(fmaf(st1[t2][r], Cc, -mC));
        union { bf16x8 v; __hip_bfloat162 h[4]; } u;
#pragma unroll
        for (int j = 0; j < 4; ++j)
          u.h[j] = __float22bfloat162_rn(make_float2(p[2 * j], p[2 * j + 1]));
        pf1 = u.v;
      }
      // ================= qt0 softmax (unconditional mask, R7-exact) =========
      bf16x8 pf0;
      if (act0) {
        const int qv = q0b + lq;
        float mx = -3e38f;
#pragma unroll
        for (int t2 = 0; t2 < 2; ++t2)
#pragma unroll
          for (int r = 0; r < 4; ++r) {
            const int key = kb + 8 * quad + 4 * t2 + r;
            const float v = (key <= qv) ? st0[t2][r] : -3e38f;
            st0[t2][r] = v;
            mx = fmaxf(mx, v);
          }
        mx = fmaxf(mx, __shfl_xor(mx, 16));
        mx = fmaxf(mx, __shfl_xor(mx, 32));
        const float mn = fmaxf(m0v, mx);
        const float al = __builtin_amdgcn_exp2f((m0v - mn) * Cc);
        m0v = mn;
        if (!__all(al == 1.0f)) {
#pragma unroll
          for (int r = 0; r < 4; ++r) lacc0[r] *= al;
#pragma unroll
          for (int mt = 0; mt < 4; ++mt)
#pragma unroll
            for (int r = 0; r < 4; ++r)
              o0[mt][r] *= al;
        }
        const float mC = mn * Cc;
        float p[8];
#pragma unroll
        for (int t2 = 0; t2 < 2; ++t2)
#pragma unroll
          for (int r = 0; r < 4; ++r)
            p[t2 * 4 + r] = __builtin_amdgcn_exp2f(fmaf(st0[t2][r], Cc, -mC));
        union { bf16x8 v; __hip_bfloat162 h[4]; } u;
#pragma unroll
        for (int j = 0; j < 4; ++j)
          u.h[j] = __float22bfloat162_rn(make_float2(p[2 * j], p[2 * j + 1]));
        pf0 = u.v;
      }
      // ---- O^T += V^T . P^T ; l += ones . P^T (row-sum on MFMA pipe)
#pragma unroll
      for (int mt = 0; mt < 4; ++mt) {
        o1[mt] = __builtin_amdgcn_mfma_f32_16x16x32_bf16(vf[mt], pf1, o1[mt], 0, 0, 0);
        if (act0)
          o0[mt] = __builtin_amdgcn_mfma_f32_16x16x32_bf16(vf[mt], pf0, o0[mt], 0, 0, 0);
      }
      lacc1 = __builtin_amdgcn_mfma_f32_16x16x32_bf16(onesf, pf1, lacc1, 0, 0, 0);
      if (act0)
        lacc0 = __builtin_amdgcn_mfma_f32_16x16x32_bf16(onesf, pf0, lacc0, 0, 0, 0);
    }
    __syncthreads();
  }

  // ---- epilogue: normalize (l = lacc[0], all regs equal), store
  {
    const float inv = 1.0f / lacc1[0];
    const int q = q1b + lq;
#pragma unroll
    for (int mt = 0; mt < 4; ++mt) {
      short4 v;
      v.x = f2bf(o1[mt][0] * inv);
      v.y = f2bf(o1[mt][1] * inv);
      v.z = f2bf(o1[mt][2] * inv);
      v.w = f2bf(o1[mt][3] * inv);
      *(short4*)(AOb + ((size_t)(b * SEQ + q)) * DM + h * HD + mt * 16 + quad * 4) = v;
    }
  }
  {
    const float inv = 1.0f / lacc0[0];
    const int q = q0b + lq;
#pragma unroll
    for (int mt = 0; mt < 4; ++mt) {
      short4 v;
      v.x = f2bf(o0[mt][0] * inv);
      v.y = f2bf(o0[mt][1] * inv);
      v.z = f2bf(o0[mt][2] * inv);
      v.w = f2bf(o0[mt][3] * inv);
      *(short4*)(AOb + ((size_t)(b * SEQ + q)) * DM + h * HD + mt * 16 + quad * 4) = v;
    }
  }
}

// ----------------------------------------------------------- output projection
__global__ __launch_bounds__(256) void out_gemm(
    const short* __restrict__ AOb, const short* __restrict__ Wob, float* __restrict__ C)
{
  __shared__ __align__(16) short As[4096], Bs[4096];
  const int m0 = blockIdx.y * 128, n0 = blockIdx.x * 128;
  f32x4 acc[4][4] = {};
  gemm_lds_core(AOb, Wob, As, Bs, m0, n0, acc);

  const int t = threadIdx.x;
  const int lane = t & 63, w = t >> 6;
  const int quad = lane >> 4, lq = lane & 15;
  const int mwb = m0 + (w & 1) * 64, nwb = n0 + (w >> 1) * 64;
#pragma unroll
  for (int mt = 0; mt < 4; ++mt)
#pragma unroll
    for (int nt = 0; nt < 4; ++nt) {
      const int n = nwb + nt * 16 + lq;
      const int mbase = mwb + mt * 16 + quad * 4;
#pragma unroll
      for (int r = 0; r < 4; ++r)
        C[(size_t)(mbase + r) * DM + n] = acc[mt][nt][r];
    }
}

// ------------------------------------------------------------------- launcher
extern "C" void kernel_launch(void* const* d_in, const int* in_sizes, int n_in,
                              void* d_out, int out_size, void* d_ws, size_t ws_size,
                              hipStream_t stream) {
  const float* x  = (const float*)d_in[0];
  const float* Wq = (const float*)d_in[1];
  const float* Wk = (const float*)d_in[2];
  const float* Wv = (const float*)d_in[3];
  const float* Wo = (const float*)d_in[4];
  float* out = (float*)d_out;

  short* xb  = (short*)d_ws;                       // 8192*768
  short* Wqb = xb  + (size_t)MTOT * DM;
  short* Wkb = Wqb + DM * DM;
  short* Wvb = Wkb + DM * DM;
  short* Wob = Wvb + DM * DM;
  short* Qb  = Wob + DM * DM;                      // (b,h,s,d)
  short* Kb  = Qb  + (size_t)MTOT * DM;            // (b,h,s,d)
  short* VTb = Kb  + (size_t)MTOT * DM;            // (b,h,d,s)
  short* AOb = xb;                                 // alias: xb dead after qkv_gemm

  const int TOT4 = (MTOT * DM + 4 * DM * DM) / 4;
  cvt5_kernel<<<(TOT4 + 255) / 256, 256, 0, stream>>>(x, Wq, Wk, Wv, Wo, xb);

  qkv_gemm<<<dim3(3 * DM / 128, MTOT / 128), 256, 0, stream>>>(xb, Wqb, Qb, Kb, VTb);
  attn_kernel<<<dim3(768), 256, 0, stream>>>(Qb, Kb, VTb, AOb);
  out_gemm<<<dim3(DM / 128, MTOT / 128), 256, 0, stream>>>(AOb, Wob, out);
}